// Round 4
// baseline (441.815 us; speedup 1.0000x reference)
//
#include <hip/hip_runtime.h>
#include <stdint.h>

#define N_NODES 50000
#define N_EDGES 800000
#define D 512
#define M_PAD 50048    // 391 * 128
#define SCAN_NB 196    // 196*256 = 50176 >= N_NODES

typedef __attribute__((ext_vector_type(8))) __bf16 bf16x8;
typedef __attribute__((ext_vector_type(4))) float f32x4;

static __device__ __forceinline__ unsigned short f2bf(float f) {
  unsigned u = __float_as_uint(f);
  u += 0x7fff + ((u >> 16) & 1);   // round-to-nearest-even
  return (unsigned short)(u >> 16);
}
static __device__ __forceinline__ float bf2f(unsigned short h) {
  return __uint_as_float(((unsigned)h) << 16);
}

// async global->LDS, 16B per lane; LDS base must be wave-uniform (lane-linear fill)
static __device__ __forceinline__ void gload_lds16(const void* g, void* l) {
  __builtin_amdgcn_global_load_lds((const __attribute__((address_space(1))) unsigned*)g,
                                   (__attribute__((address_space(3))) unsigned*)l, 16, 0, 0);
}

// ---- X (fp32, N_NODES x D) -> bf16, zero-padded to M_PAD rows; also zeroes deg ----
__global__ void k_cvt_x(const float* __restrict__ x, unsigned short* __restrict__ xb,
                        int* __restrict__ deg) {
  long long gid = (long long)blockIdx.x * blockDim.x + threadIdx.x;
  if (gid < N_NODES) deg[(int)gid] = 0;   // folded k_zero
  long long base = gid * 4;
  if (base >= (long long)M_PAD * D) return;
  int row = (int)(base >> 9);  // D = 512
  ushort4 o;
  if (row < N_NODES) {
    float4 v = *(const float4*)(x + base);
    o.x = f2bf(v.x); o.y = f2bf(v.y); o.z = f2bf(v.z); o.w = f2bf(v.w);
  } else {
    o.x = 0; o.y = 0; o.z = 0; o.w = 0;
  }
  *(ushort4*)(xb + base) = o;
}

// ---- W (fp32, K x N row-major) -> Wt bf16 (N x K); coalesced WRITE, strided read (W is L2-resident) ----
__global__ void k_cvt_wt(const float* __restrict__ w, unsigned short* __restrict__ wt) {
  int n = blockIdx.x;     // 512 blocks  (output row of Wt)
  int k = threadIdx.x;    // 512 threads (contiguous in Wt row -> coalesced store)
  wt[n * D + k] = f2bf(w[k * D + n]);
}

// ---- bf16 GEMM: C[M_PAD x D] = A * Bt^T, 128x128 tile ----
// Double-buffered K-pipeline: stage tile kt+1 (global_load_lds) BEFORE computing tile kt;
// one __syncthreads (vmcnt+lgkm drain) per K-step instead of two serial barriers.
__global__ __launch_bounds__(256) void k_gemm(const unsigned short* __restrict__ A,
                                              const unsigned short* __restrict__ Bt,
                                              unsigned short* __restrict__ C) {
  __shared__ unsigned short lds_a[2][128 * 32];
  __shared__ unsigned short lds_b[2][128 * 32];
  const int tid  = threadIdx.x;
  const int bm   = blockIdx.x >> 2;   // 391
  const int bn   = blockIdx.x & 3;    // 4
  const int m0   = bm * 128, n0 = bn * 128;
  const int wave = tid >> 6, lane = tid & 63;
  const int wm   = wave & 1, wn = wave >> 1;
  const int l15  = lane & 15, quad = lane >> 4;

  // staging geometry (hoisted): chunk id i -> row, k-offset
  const int i0 = wave * 64 + lane;
  const int r0 = i0 >> 2, kc0 = (i0 & 3) << 3;
  const int i1 = 256 + wave * 64 + lane;
  const int r1 = i1 >> 2, kc1 = (i1 & 3) << 3;

  f32x4 acc[4][4];
#pragma unroll
  for (int i = 0; i < 4; i++)
#pragma unroll
    for (int j = 0; j < 4; j++) acc[i][j] = f32x4{0.f, 0.f, 0.f, 0.f};

#define STAGE(KT, B)                                                                       \
  do {                                                                                     \
    const int k0_ = (KT) * 32;                                                             \
    gload_lds16(&A [(long long)(m0 + r0) * D + k0_ + kc0], &lds_a[B][(wave * 64) * 8]);    \
    gload_lds16(&Bt[(long long)(n0 + r0) * D + k0_ + kc0], &lds_b[B][(wave * 64) * 8]);    \
    gload_lds16(&A [(long long)(m0 + r1) * D + k0_ + kc1], &lds_a[B][(256 + wave * 64) * 8]); \
    gload_lds16(&Bt[(long long)(n0 + r1) * D + k0_ + kc1], &lds_b[B][(256 + wave * 64) * 8]); \
  } while (0)

  STAGE(0, 0);
  __syncthreads();   // tile 0 resident

#pragma unroll 2
  for (int kt = 0; kt < D / 32; ++kt) {
    const int cur = kt & 1;
    if (kt + 1 < D / 32) STAGE(kt + 1, cur ^ 1);   // prefetch overlaps this tile's compute
    bf16x8 af[4], bfr[4];
#pragma unroll
    for (int t = 0; t < 4; t++) {
      af[t]  = *(const bf16x8*)&lds_a[cur][(wm * 64 + t * 16 + l15) * 32 + quad * 8];
      bfr[t] = *(const bf16x8*)&lds_b[cur][(wn * 64 + t * 16 + l15) * 32 + quad * 8];
    }
#pragma unroll
    for (int i = 0; i < 4; i++)
#pragma unroll
      for (int j = 0; j < 4; j++)
        acc[i][j] = __builtin_amdgcn_mfma_f32_16x16x32_bf16(af[i], bfr[j], acc[i][j], 0, 0, 0);
    __syncthreads();   // drains vmcnt (next tile staged) + lgkm; guards buffer reuse
  }
#undef STAGE

#pragma unroll
  for (int i = 0; i < 4; i++)
#pragma unroll
    for (int j = 0; j < 4; j++)
#pragma unroll
      for (int r = 0; r < 4; r++) {
        int row = m0 + wm * 64 + i * 16 + quad * 4 + r;
        int col = n0 + wn * 64 + j * 16 + l15;
        C[(long long)row * D + col] = f2bf(acc[i][j][r]);
      }
}

// ---- CSR-by-destination build ----
__global__ void k_hist(const int* __restrict__ dst, int* deg) {
  int e = blockIdx.x * 256 + threadIdx.x;
  if (e < N_EDGES) atomicAdd(&deg[dst[e]], 1);
}

__global__ void k_scan1(const int* __restrict__ deg, int* __restrict__ bsum) {
  __shared__ int red[256];
  int i = blockIdx.x * 256 + threadIdx.x;
  red[threadIdx.x] = (i < N_NODES) ? deg[i] : 0;
  __syncthreads();
#pragma unroll
  for (int s = 128; s > 0; s >>= 1) {
    if ((int)threadIdx.x < s) red[threadIdx.x] += red[threadIdx.x + s];
    __syncthreads();
  }
  if (threadIdx.x == 0) bsum[blockIdx.x] = red[0];
}
__global__ void k_scan2(int* __restrict__ bsum) {   // 1 block, 256 threads
  __shared__ int tmp[256];
  int t = threadIdx.x;
  int v = (t < SCAN_NB) ? bsum[t] : 0;
  tmp[t] = v;
  __syncthreads();
#pragma unroll
  for (int s = 1; s < 256; s <<= 1) {
    int add = (t >= s) ? tmp[t - s] : 0;
    __syncthreads();
    tmp[t] += add;
    __syncthreads();
  }
  if (t < SCAN_NB) bsum[t] = tmp[t] - v;   // exclusive
}
__global__ void k_scan3(const int* __restrict__ deg, const int* __restrict__ bsum,
                        int* __restrict__ off, int* __restrict__ cur) {
  __shared__ int tmp[256];
  int t = threadIdx.x, i = blockIdx.x * 256 + t;
  int v = (i < N_NODES) ? deg[i] : 0;
  tmp[t] = v;
  __syncthreads();
#pragma unroll
  for (int s = 1; s < 256; s <<= 1) {
    int add = (t >= s) ? tmp[t - s] : 0;
    __syncthreads();
    tmp[t] += add;
    __syncthreads();
  }
  int pre = tmp[t] - v + bsum[blockIdx.x];
  if (i < N_NODES) {
    off[i] = pre;
    cur[i] = pre;
    if (i == N_NODES - 1) off[N_NODES] = pre + v;
  }
}

// interleaved edge payload: one 8B store per edge (one cache line touched, not two)
__global__ void k_fill(const int* __restrict__ src, const int* __restrict__ dst,
                       const float* __restrict__ w, int* cur, int2* __restrict__ cew) {
  int e = blockIdx.x * 256 + threadIdx.x;
  if (e >= N_EDGES) return;
  int d = dst[e];
  int p = atomicAdd(&cur[d], 1);
  cew[p] = make_int2(src[e], __float_as_int(w[e]));
}

// ---- aggregate: ONE WAVE per node, 6-deep gather pipeline (<=64 VGPR keeps 8 waves/SIMD) ----
__global__ __launch_bounds__(256) void k_agg(const int* __restrict__ off,
                                             const int2* __restrict__ cew,
                                             const unsigned short* __restrict__ S,
                                             float* __restrict__ out) {
  const int wave = threadIdx.x >> 6, lane = threadIdx.x & 63;
  const int node = blockIdx.x * 4 + wave;          // grid = 12500, 4*12500 = 50000 exact
  const int start = off[node], end = off[node + 1];
  float a[8];
#pragma unroll
  for (int k = 0; k < 8; k++) a[k] = 0.f;

#define EDGE_FMA(V, W)                                             \
  do {                                                             \
    a[0] = fmaf(W, bf2f((unsigned short)(V.x & 0xffffu)), a[0]);   \
    a[1] = fmaf(W, bf2f((unsigned short)(V.x >> 16)),     a[1]);   \
    a[2] = fmaf(W, bf2f((unsigned short)(V.y & 0xffffu)), a[2]);   \
    a[3] = fmaf(W, bf2f((unsigned short)(V.y >> 16)),     a[3]);   \
    a[4] = fmaf(W, bf2f((unsigned short)(V.z & 0xffffu)), a[4]);   \
    a[5] = fmaf(W, bf2f((unsigned short)(V.z >> 16)),     a[5]);   \
    a[6] = fmaf(W, bf2f((unsigned short)(V.w & 0xffffu)), a[6]);   \
    a[7] = fmaf(W, bf2f((unsigned short)(V.w >> 16)),     a[7]);   \
  } while (0)

#define GATHER(P) (*(const uint4*)(S + (size_t)(P).x * D + lane * 8))

  int e = start;
  // 6-deep pipeline: 6 independent 1KB row gathers in flight per wave
  for (; e + 5 < end; e += 6) {
    int2 q0 = cew[e],     q1 = cew[e + 1], q2 = cew[e + 2];
    int2 q3 = cew[e + 3], q4 = cew[e + 4], q5 = cew[e + 5];
    uint4 v0 = GATHER(q0);
    uint4 v1 = GATHER(q1);
    uint4 v2 = GATHER(q2);
    uint4 v3 = GATHER(q3);
    uint4 v4 = GATHER(q4);
    uint4 v5 = GATHER(q5);
    EDGE_FMA(v0, __int_as_float(q0.y));
    EDGE_FMA(v1, __int_as_float(q1.y));
    EDGE_FMA(v2, __int_as_float(q2.y));
    EDGE_FMA(v3, __int_as_float(q3.y));
    EDGE_FMA(v4, __int_as_float(q4.y));
    EDGE_FMA(v5, __int_as_float(q5.y));
  }
  // tail: predicated 4-batches, dummies re-read q0's row with weight 0 (L1-hit, adds 0)
  for (; e < end; e += 4) {
    int2 q0 = cew[e];
    int2 q1 = (e + 1 < end) ? cew[e + 1] : make_int2(q0.x, 0);
    int2 q2 = (e + 2 < end) ? cew[e + 2] : make_int2(q0.x, 0);
    int2 q3 = (e + 3 < end) ? cew[e + 3] : make_int2(q0.x, 0);
    uint4 v0 = GATHER(q0);
    uint4 v1 = GATHER(q1);
    uint4 v2 = GATHER(q2);
    uint4 v3 = GATHER(q3);
    EDGE_FMA(v0, __int_as_float(q0.y));
    EDGE_FMA(v1, __int_as_float(q1.y));
    EDGE_FMA(v2, __int_as_float(q2.y));
    EDGE_FMA(v3, __int_as_float(q3.y));
  }
#undef GATHER
#undef EDGE_FMA

  // coalesced row store; non-temporal (out never re-read; keep L2/L3 for S)
  f32x4 o0 = {a[0], a[1], a[2], a[3]};
  f32x4 o1 = {a[4], a[5], a[6], a[7]};
  f32x4* op = (f32x4*)(out + (size_t)node * D + lane * 8);
  __builtin_nontemporal_store(o0, op);
  __builtin_nontemporal_store(o1, op + 1);
}

extern "C" void kernel_launch(void* const* d_in, const int* in_sizes, int n_in,
                              void* d_out, int out_size, void* d_ws, size_t ws_size,
                              hipStream_t stream) {
  const float* x    = (const float*)d_in[0];
  const float* w    = (const float*)d_in[1];
  const float* ew   = (const float*)d_in[2];
  const int*   esrc = (const int*)d_in[3];
  const int*   edst = (const int*)d_in[4];
  float* out = (float*)d_out;

  char* p = (char*)d_ws;
  auto align256 = [](size_t v) { return (v + 255) & ~(size_t)255; };
  unsigned short* xb = (unsigned short*)p;  p += align256((size_t)M_PAD * D * 2);
  unsigned short* sb = (unsigned short*)p;  p += align256((size_t)M_PAD * D * 2);
  unsigned short* wt = (unsigned short*)p;  p += align256((size_t)D * D * 2);
  int*   deg  = (int*)p;   p += align256((size_t)N_NODES * 4);
  int*   off  = (int*)p;   p += align256((size_t)(N_NODES + 1) * 4);
  int*   cur  = (int*)p;   p += align256((size_t)N_NODES * 4);
  int2*  cew  = (int2*)p;  p += align256((size_t)N_EDGES * 8);
  int*   bsum = (int*)p;   p += align256((size_t)256 * 4);

  // stage 0: casts (deg zeroing folded into k_cvt_x)
  k_cvt_x<<<(M_PAD * D / 4 + 255) / 256, 256, 0, stream>>>(x, xb, deg);
  k_cvt_wt<<<D, D, 0, stream>>>(w, wt);
  // stage 1: support = X @ W  (bf16 MFMA, output bf16, double-buffered pipeline)
  k_gemm<<<391 * 4, 256, 0, stream>>>(xb, wt, sb);
  // stage 2a: CSR build by destination (parallel scan)
  k_hist<<<(N_EDGES + 255) / 256, 256, 0, stream>>>(edst, deg);
  k_scan1<<<SCAN_NB, 256, 0, stream>>>(deg, bsum);
  k_scan2<<<1, 256, 0, stream>>>(bsum);
  k_scan3<<<SCAN_NB, 256, 0, stream>>>(deg, bsum, off, cur);
  k_fill<<<(N_EDGES + 255) / 256, 256, 0, stream>>>(esrc, edst, ew, cur, cew);
  // stage 2b: aggregate, one WAVE per node, 6-deep gather pipeline
  k_agg<<<N_NODES / 4, 256, 0, stream>>>(off, cew, sb, out);
}

// Round 5
// 378.112 us; speedup vs baseline: 1.1685x; 1.1685x over previous
//
#include <hip/hip_runtime.h>
#include <stdint.h>

#define N_NODES 50000
#define N_EDGES 800000
#define D 512
#define M_PAD 50048    // 391 * 128
#define CAP 64         // bucket slots per node; Poisson(16) overflow ~1e-18
#define CAPSH 6

// mega-kernel block-role ranges (256 threads each)
#define FILL_NB 3125   // 3125*256 = 800000 exact
#define WT_NB   1024   // 1024 blocks * 256 thr = 262144 = D*D
#define CVT_NB  25024  // 25024*256*4 = M_PAD*D exact

typedef __attribute__((ext_vector_type(8))) __bf16 bf16x8;
typedef __attribute__((ext_vector_type(4))) float f32x4;

static __device__ __forceinline__ unsigned short f2bf(float f) {
  unsigned u = __float_as_uint(f);
  u += 0x7fff + ((u >> 16) & 1);   // round-to-nearest-even
  return (unsigned short)(u >> 16);
}
static __device__ __forceinline__ float bf2f(unsigned short h) {
  return __uint_as_float(((unsigned)h) << 16);
}

// async global->LDS, 16B per lane; LDS base must be wave-uniform (lane-linear fill)
static __device__ __forceinline__ void gload_lds16(const void* g, void* l) {
  __builtin_amdgcn_global_load_lds((const __attribute__((address_space(1))) unsigned*)g,
                                   (__attribute__((address_space(3))) unsigned*)l, 16, 0, 0);
}

// ---- fused: edge-bucket fill (atomic, latency-bound) + W transpose-cast + X cast ----
// fill blocks first so their atomics overlap the bandwidth-bound cvt blocks.
__global__ __launch_bounds__(256) void k_mega(const float* __restrict__ x,
                                              const float* __restrict__ w,
                                              const float* __restrict__ ew,
                                              const int* __restrict__ esrc,
                                              const int* __restrict__ edst,
                                              unsigned short* __restrict__ xb,
                                              unsigned short* __restrict__ wt,
                                              int* __restrict__ cur,
                                              int2* __restrict__ cew) {
  int bid = blockIdx.x;
  if (bid < FILL_NB) {
    int e = bid * 256 + threadIdx.x;   // e < 800000 always (exact grid)
    int d = edst[e];
    int r = atomicAdd(&cur[d], 1);
    if (r < CAP) cew[(d << CAPSH) + r] = make_int2(esrc[e], __float_as_int(ew[e]));
    return;
  }
  bid -= FILL_NB;
  if (bid < WT_NB) {
    int n = bid >> 1;                          // wt row
    int k = ((bid & 1) << 8) + threadIdx.x;    // coalesced write along wt row
    wt[n * D + k] = f2bf(w[k * D + n]);        // strided read; W is 1MB, L2-resident
    return;
  }
  bid -= WT_NB;
  // X cast: fp32 -> bf16, zero-pad rows [N_NODES, M_PAD)
  long long base = ((long long)bid * 256 + threadIdx.x) * 4;
  int row = (int)(base >> 9);  // D = 512
  ushort4 o;
  if (row < N_NODES) {
    float4 v = *(const float4*)(x + base);
    o.x = f2bf(v.x); o.y = f2bf(v.y); o.z = f2bf(v.z); o.w = f2bf(v.w);
  } else {
    o.x = 0; o.y = 0; o.z = 0; o.w = 0;
  }
  *(ushort4*)(xb + base) = o;
}

// ---- bf16 GEMM: C[M_PAD x D] = A * Bt^T, 128x128 tile, global_load_lds staging ----
__global__ __launch_bounds__(256) void k_gemm(const unsigned short* __restrict__ A,
                                              const unsigned short* __restrict__ Bt,
                                              unsigned short* __restrict__ C) {
  __shared__ unsigned short lds_a[128 * 32];
  __shared__ unsigned short lds_b[128 * 32];
  const int tid  = threadIdx.x;
  const int bm   = blockIdx.x >> 2;   // 391
  const int bn   = blockIdx.x & 3;    // 4
  const int m0   = bm * 128, n0 = bn * 128;
  const int wave = tid >> 6, lane = tid & 63;
  const int wm   = wave & 1, wn = wave >> 1;
  const int l15  = lane & 15, quad = lane >> 4;

  f32x4 acc[4][4];
#pragma unroll
  for (int i = 0; i < 4; i++)
#pragma unroll
    for (int j = 0; j < 4; j++) acc[i][j] = f32x4{0.f, 0.f, 0.f, 0.f};

  for (int kt = 0; kt < D / 32; ++kt) {
    const int k0 = kt * 32;
    __syncthreads();
#pragma unroll
    for (int c = 0; c < 2; c++) {
      int i = c * 256 + wave * 64 + lane;   // 16B chunk id, lane-linear per wave
      int r = i >> 2, kc = (i & 3) << 3;
      gload_lds16(&A[(long long)(m0 + r) * D + k0 + kc], &lds_a[(c * 256 + wave * 64) * 8]);
      gload_lds16(&Bt[(long long)(n0 + r) * D + k0 + kc], &lds_b[(c * 256 + wave * 64) * 8]);
    }
    __syncthreads();
    bf16x8 af[4], bfr[4];
#pragma unroll
    for (int t = 0; t < 4; t++) {
      af[t]  = *(const bf16x8*)&lds_a[(wm * 64 + t * 16 + l15) * 32 + quad * 8];
      bfr[t] = *(const bf16x8*)&lds_b[(wn * 64 + t * 16 + l15) * 32 + quad * 8];
    }
#pragma unroll
    for (int i = 0; i < 4; i++)
#pragma unroll
      for (int j = 0; j < 4; j++)
        acc[i][j] = __builtin_amdgcn_mfma_f32_16x16x32_bf16(af[i], bfr[j], acc[i][j], 0, 0, 0);
  }
#pragma unroll
  for (int i = 0; i < 4; i++)
#pragma unroll
    for (int j = 0; j < 4; j++)
#pragma unroll
      for (int r = 0; r < 4; r++) {
        int row = m0 + wm * 64 + i * 16 + quad * 4 + r;
        int col = n0 + wn * 64 + j * 16 + l15;
        C[(long long)row * D + col] = f2bf(acc[i][j][r]);
      }
}

// ---- aggregate: one BLOCK per node (round-0 structure: best measured), bucket CSR ----
__global__ __launch_bounds__(256) void k_agg(const int* __restrict__ cur,
                                             const int2* __restrict__ cew,
                                             const unsigned short* __restrict__ S,
                                             float* __restrict__ out) {
  __shared__ float s_part[4 * 512];
  const int node  = blockIdx.x;
  int cnt = cur[node];
  cnt = (cnt > CAP) ? CAP : cnt;             // memory-safety clamp (P(overflow)~1e-18)
  const int start = node << CAPSH, end = start + cnt;
  const int wave  = threadIdx.x >> 6, lane = threadIdx.x & 63;
  float a[8];
#pragma unroll
  for (int k = 0; k < 8; k++) a[k] = 0.f;

#define EDGE_FMA(V, W)                                             \
  do {                                                             \
    a[0] = fmaf(W, bf2f((unsigned short)(V.x & 0xffffu)), a[0]);   \
    a[1] = fmaf(W, bf2f((unsigned short)(V.x >> 16)),     a[1]);   \
    a[2] = fmaf(W, bf2f((unsigned short)(V.y & 0xffffu)), a[2]);   \
    a[3] = fmaf(W, bf2f((unsigned short)(V.y >> 16)),     a[3]);   \
    a[4] = fmaf(W, bf2f((unsigned short)(V.z & 0xffffu)), a[4]);   \
    a[5] = fmaf(W, bf2f((unsigned short)(V.z >> 16)),     a[5]);   \
    a[6] = fmaf(W, bf2f((unsigned short)(V.w & 0xffffu)), a[6]);   \
    a[7] = fmaf(W, bf2f((unsigned short)(V.w >> 16)),     a[7]);   \
  } while (0)

#define GATHER(P) (*(const uint4*)(S + (size_t)(P).x * D + lane * 8))

  int e = start + wave;
  // 2-deep pipelined pairs across 4 waves (8 rows in flight per block)
  for (; e + 4 < end; e += 8) {
    int2 p0 = cew[e], p1 = cew[e + 4];
    uint4 v0 = GATHER(p0);
    uint4 v1 = GATHER(p1);
    EDGE_FMA(v0, __int_as_float(p0.y));
    EDGE_FMA(v1, __int_as_float(p1.y));
  }
  if (e < end) {
    int2 p0 = cew[e];
    uint4 v0 = GATHER(p0);
    EDGE_FMA(v0, __int_as_float(p0.y));
  }
#undef GATHER
#undef EDGE_FMA

  // cross-wave combine
  float4* sp = (float4*)&s_part[wave * 512 + lane * 8];
  sp[0] = make_float4(a[0], a[1], a[2], a[3]);
  sp[1] = make_float4(a[4], a[5], a[6], a[7]);
  __syncthreads();
  int col = threadIdx.x * 2;
  float2 r0 = *(const float2*)&s_part[0 * 512 + col];
  float2 r1 = *(const float2*)&s_part[1 * 512 + col];
  float2 r2 = *(const float2*)&s_part[2 * 512 + col];
  float2 r3 = *(const float2*)&s_part[3 * 512 + col];
  float2 res = make_float2(r0.x + r1.x + r2.x + r3.x, r0.y + r1.y + r2.y + r3.y);
  // non-temporal 8B store (out never re-read; keep L2/L3 for S)
  typedef __attribute__((ext_vector_type(2))) float f32x2;
  f32x2 rv = {res.x, res.y};
  __builtin_nontemporal_store(rv, (f32x2*)(out + (size_t)node * D + col));
}

extern "C" void kernel_launch(void* const* d_in, const int* in_sizes, int n_in,
                              void* d_out, int out_size, void* d_ws, size_t ws_size,
                              hipStream_t stream) {
  const float* x    = (const float*)d_in[0];
  const float* w    = (const float*)d_in[1];
  const float* ew   = (const float*)d_in[2];
  const int*   esrc = (const int*)d_in[3];
  const int*   edst = (const int*)d_in[4];
  float* out = (float*)d_out;

  char* p = (char*)d_ws;
  auto align256 = [](size_t v) { return (v + 255) & ~(size_t)255; };
  unsigned short* xb = (unsigned short*)p;  p += align256((size_t)M_PAD * D * 2);
  unsigned short* sb = (unsigned short*)p;  p += align256((size_t)M_PAD * D * 2);
  unsigned short* wt = (unsigned short*)p;  p += align256((size_t)D * D * 2);
  int*   cur  = (int*)p;   p += align256((size_t)N_NODES * 4);
  int2*  cew  = (int2*)p;  p += align256((size_t)N_NODES * CAP * 8);

  // bucket counters must be zero before the fused fill blocks run
  hipMemsetAsync(cur, 0, (size_t)N_NODES * 4, stream);
  // fused: bucket-fill (atomic placement) + W^T cast + X cast
  k_mega<<<FILL_NB + WT_NB + CVT_NB, 256, 0, stream>>>(x, w, ew, esrc, edst, xb, wt, cur, cew);
  // support = X @ W  (bf16 MFMA, output bf16)
  k_gemm<<<391 * 4, 256, 0, stream>>>(xb, wt, sb);
  // aggregate: one block per node, fixed-capacity bucket CSR
  k_agg<<<N_NODES, 256, 0, stream>>>(cur, cew, sb, out);
}